// Round 1
// baseline (5550.415 us; speedup 1.0000x reference)
//
#include <hip/hip_runtime.h>
#include <stdint.h>
#include <string.h>

// Problem constants
#define NT 1024
#define NB 64
#define ND 128
#define NH 512

typedef float f32x4  __attribute__((ext_vector_type(4)));
typedef short bf16x8 __attribute__((ext_vector_type(8)));

// round-to-nearest-even f32 -> bf16 (no NaN handling needed; data is tame)
__device__ __forceinline__ short f2bf(float f) {
  uint32_t u = __float_as_uint(f);
  u += 0x7fffu + ((u >> 16) & 1u);
  return (short)(u >> 16);
}

__device__ __forceinline__ bf16x8 cvt8(f32x4 a, f32x4 b) {
  bf16x8 r;
  r[0] = f2bf(a[0]); r[1] = f2bf(a[1]); r[2] = f2bf(a[2]); r[3] = f2bf(a[3]);
  r[4] = f2bf(b[0]); r[5] = f2bf(b[1]); r[6] = f2bf(b[2]); r[7] = f2bf(b[3]);
  return r;
}

// Persistent RNN kernel.
// Grid: 32 WGs x 256 threads. WG wg: rg = wg>>3 (16 batch rows), cg = wg&7 (64 cols).
// Each wave (wv=0..3) owns a 16x16 output tile: rows b = rg*16+{0..15}, cols
// g = cg*64 + wv*16 + {0..15}. W_hid/W_in B-fragments live in VGPRs (bf16).
// fr_t moves between the 8 WGs of a row-group via a double-buffered bf16
// global buffer + per-WG monotone flags (agent scope).
__global__ __launch_bounds__(256, 1) void rnn_persistent(
    const float* __restrict__ input,   // [T,B,D]
    const float* __restrict__ W_in,    // [H,D]
    const float* __restrict__ b_in,    // [H]
    const float* __restrict__ W_hid,   // [H,H]
    const float* __restrict__ b_hid,   // [H]
    float* __restrict__ out,           // [T,B,H] fp32
    int* __restrict__ flags,           // 32 flags, stride 32 ints (128B lines)
    unsigned short* __restrict__ frbuf)// [2][B][H] bf16
{
  const int wg   = blockIdx.x;   // 0..31
  const int rg   = wg >> 3;      // row group 0..3
  const int cg   = wg & 7;       // col group 0..7
  const int tid  = threadIdx.x;
  const int wv   = tid >> 6;     // wave 0..3
  const int lane = tid & 63;
  const int col  = lane & 15;
  const int quad = lane >> 4;
  const int kq   = quad * 8;     // k offset inside a 32-wide K chunk

  const int bA = rg * 16 + col;           // A-fragment batch row (m = lane&15)
  const int gB = cg * 64 + wv * 16 + col; // B-fragment / C column (n = lane&15)
  const int bC = rg * 16 + quad * 4;      // C rows: bC + r, r=0..3

  // ---- stationary weights: B-fragments in registers (bf16) ----
  bf16x8 Bh[16];   // W_hid: B[n=g][k=h], 16 K-chunks of 32
#pragma unroll
  for (int kk = 0; kk < 16; ++kk) {
    const float* p = W_hid + (size_t)gB * NH + kk * 32 + kq;
    Bh[kk] = cvt8(*(const f32x4*)p, *(const f32x4*)(p + 4));
  }
  bf16x8 Bi[4];    // W_in: B[n=g][k=d], 4 K-chunks of 32
#pragma unroll
  for (int kk = 0; kk < 4; ++kk) {
    const float* p = W_in + (size_t)gB * ND + kk * 32 + kq;
    Bi[kk] = cvt8(*(const f32x4*)p, *(const f32x4*)(p + 4));
  }
  const float blane = b_hid[gB] + b_in[gB];  // both biases enter v identically

  // membrane potential, persistent in C-layout registers
  float v0 = 0.f, v1 = 0.f, v2 = 0.f, v3 = 0.f;

#pragma unroll 1
  for (int t = 0; t < NT; ++t) {
    // Prefetch this step's input slice BEFORE the peer wait (independent of fr).
    const float* ip = input + ((size_t)t * NB + bA) * ND + kq;
    f32x4 x0 = *(const f32x4*)(ip);
    f32x4 x1 = *(const f32x4*)(ip + 4);
    f32x4 x2 = *(const f32x4*)(ip + 32);
    f32x4 x3 = *(const f32x4*)(ip + 36);
    f32x4 x4 = *(const f32x4*)(ip + 64);
    f32x4 x5 = *(const f32x4*)(ip + 68);
    f32x4 x6 = *(const f32x4*)(ip + 96);
    f32x4 x7 = *(const f32x4*)(ip + 100);

    if (t > 0) {
      // wait until all 8 row-group peers have published fr_t (flag >= t).
      // Poison 0xAAAAAAAA is negative as int -> blocks correctly, no init.
      if (tid < 8) {
        const int* fp = flags + (rg * 8 + tid) * 32;
        while (__hip_atomic_load(fp, __ATOMIC_RELAXED,
                                 __HIP_MEMORY_SCOPE_AGENT) < t) { }
      }
      __syncthreads();
      __builtin_amdgcn_fence(__ATOMIC_ACQUIRE, "agent"); // invalidate stale L1/L2
    }

    // input-projection MFMAs (x was prefetched; cvt hides under fr loads)
    f32x4 acc = {0.f, 0.f, 0.f, 0.f};
    acc = __builtin_amdgcn_mfma_f32_16x16x32_bf16(cvt8(x0, x1), Bi[0], acc, 0, 0, 0);
    acc = __builtin_amdgcn_mfma_f32_16x16x32_bf16(cvt8(x2, x3), Bi[1], acc, 0, 0, 0);
    acc = __builtin_amdgcn_mfma_f32_16x16x32_bf16(cvt8(x4, x5), Bi[2], acc, 0, 0, 0);
    acc = __builtin_amdgcn_mfma_f32_16x16x32_bf16(cvt8(x6, x7), Bi[3], acc, 0, 0, 0);

    // recurrent MFMAs: fr_t (bf16) from the parity-(t&1) slot. t=0: fr=0, skip.
    if (t > 0) {
      const unsigned short* fr =
          frbuf + ((size_t)(t & 1) * NB + bA) * NH + kq;
#pragma unroll
      for (int kk = 0; kk < 16; ++kk) {
        bf16x8 a = *(const bf16x8*)(fr + kk * 32);
        acc = __builtin_amdgcn_mfma_f32_16x16x32_bf16(a, Bh[kk], acc, 0, 0, 0);
      }
    }

    // v = 0.9 v + 0.1 (S + u + b_hid + b_in); fr = relu(v)
    v0 = 0.9f * v0 + 0.1f * (acc[0] + blane);
    v1 = 0.9f * v1 + 0.1f * (acc[1] + blane);
    v2 = 0.9f * v2 + 0.1f * (acc[2] + blane);
    v3 = 0.9f * v3 + 0.1f * (acc[3] + blane);
    float f0 = fmaxf(v0, 0.f), f1 = fmaxf(v1, 0.f);
    float f2 = fmaxf(v2, 0.f), f3 = fmaxf(v3, 0.f);

    // stream output (fp32) — every (t,b,g) written exactly once
    float* op = out + ((size_t)t * NB + bC) * NH + gB;
    op[0]      = f0;
    op[NH]     = f1;
    op[2 * NH] = f2;
    op[3 * NH] = f3;

    // publish fr_{t+1} (bf16) into the other slot. Safe: our wait on flag>=t
    // guarantees peers finished READING this slot (their step t-1).
    unsigned short* fw =
        frbuf + ((size_t)((t + 1) & 1) * NB + bC) * NH + gB;
    fw[0]      = (unsigned short)f2bf(f0);
    fw[NH]     = (unsigned short)f2bf(f1);
    fw[2 * NH] = (unsigned short)f2bf(f2);
    fw[3 * NH] = (unsigned short)f2bf(f3);

    __syncthreads();  // drains each wave's vmcnt -> all WG stores in L2
    if (tid == 0) {
      // release: wbl2 (flush to coherence point) then flag store
      __hip_atomic_store(flags + wg * 32, t + 1, __ATOMIC_RELEASE,
                         __HIP_MEMORY_SCOPE_AGENT);
    }
  }
}

extern "C" void kernel_launch(void* const* d_in, const int* in_sizes, int n_in,
                              void* d_out, int out_size, void* d_ws, size_t ws_size,
                              hipStream_t stream) {
  const float* input = (const float*)d_in[0];  // [T,B,D]
  const float* W_in  = (const float*)d_in[1];  // [H,D]
  const float* b_in  = (const float*)d_in[2];  // [H]
  const float* W_hid = (const float*)d_in[3];  // [H,H]
  const float* b_hid = (const float*)d_in[4];  // [H]
  float* out = (float*)d_out;

  // workspace layout: [0,4KB) flags (32 x 128B-strided ints, poison = negative
  // = "not ready", so no init launch needed), [8KB, 8KB+128KB) fr double buffer.
  int* flags = (int*)d_ws;
  unsigned short* frbuf = (unsigned short*)((char*)d_ws + 8192);

  hipLaunchKernelGGL(rnn_persistent, dim3(32), dim3(256), 0, stream,
                     input, W_in, b_in, W_hid, b_hid, out, flags, frbuf);
}